// Round 8
// baseline (161.838 us; speedup 1.0000x reference)
//
#include <hip/hip_runtime.h>
#include <math.h>

typedef _Float16 f16;
typedef __attribute__((ext_vector_type(8))) _Float16 half8;
typedef __attribute__((ext_vector_type(2))) _Float16 half2v;
typedef __attribute__((ext_vector_type(4))) float f32x4;
typedef __attribute__((ext_vector_type(4))) float f4;

#define TPQ 24
#define BQ 128
#define LSQ 168

#if __has_builtin(__builtin_amdgcn_fdot2)
#define HAS_FDOT2 1
#else
#define HAS_FDOT2 0
#endif

// ws element offsets (fp16 elements)
#define E0 0        /* w01 frags */
#define ED 24576    /* wd0 */
#define E1 32768    /* w02 */
#define E2 81920    /* w11 */
#define E3 131072   /* w12 */
#define E4 180224   /* w21 */
#define E5 229376   /* w22 */
#define WTOT 278528
#define OG2 278528                       /* block2 out: [128][160][128], abs pos p-32 */
#define OG1 2899968                      /* block1 out: [128][56][128]  */
#define OG0 3817472                      /* block0 out: [128][40][128]  */
/* end: 4472832 el = 8.95 MB */

#define MFMA16(a, b, c) __builtin_amdgcn_mfma_f32_16x16x32_f16((a), (b), (c), 0, 0, 0)

// ---------------- weight fragment packing ----------------
extern "C" __global__ void pack_weights(
    const float* __restrict__ w01, const float* __restrict__ wd0,
    const float* __restrict__ w02, const float* __restrict__ w11,
    const float* __restrict__ w12, const float* __restrict__ w21,
    const float* __restrict__ w22, f16* __restrict__ ws)
{
    int e = blockIdx.x * 256 + threadIdx.x;
    if (e >= WTOT) return;
    const float* W; int CIN, KK, el;
    if (e < ED) { W = w01; CIN = 64; KK = 3; el = e; }
    else if (e < E1) { W = wd0; CIN = 64; KK = 1; el = e - ED; }
    else {
        int c = (e - E1) / 49152; el = (e - E1) % 49152; CIN = 128; KK = 3;
        W = (c == 0) ? w02 : (c == 1) ? w11 : (c == 2) ? w12 : (c == 3) ? w21 : w22;
    }
    const int KB = CIN / 32;
    const int frag = el >> 9, wi = el & 511, lane = wi >> 3, i = wi & 7;
    const int coT = frag / (KK * KB), rem = frag % (KK * KB);
    const int kk = rem / KB, kb = rem % KB;
    const int co = coT * 16 + (lane & 15);
    const int ci = kb * 32 + (lane >> 4) * 8 + i;
    ws[e] = (f16)W[(co * CIN + ci) * KK + kk];
}

// ---------------- kernel A: global TCN over full srctrg ----------------
template<int CIN, int KK, int DIL, int RES, int RELU>
__device__ __forceinline__ void phaseA(
    const char* __restrict__ inb, char* __restrict__ outb,
    const f16* __restrict__ ws, int eoff, const float* __restrict__ bias, int tid)
{
    constexpr int KB = CIN / 32;
    constexpr int RB = CIN * 2;
    const int lane = tid & 63, wid = tid >> 6;
    const int cg = wid & 3, wg = wid >> 2;
    const int colr = lane & 15, quad = lane >> 4;
    const half8* __restrict__ wp = (const half8*)(ws + eoff);
    half8 wf[2][KK][KB];
#pragma unroll
    for (int ct = 0; ct < 2; ++ct)
#pragma unroll
        for (int kk = 0; kk < KK; ++kk)
#pragma unroll
            for (int kb = 0; kb < KB; ++kb)
                wf[ct][kk][kb] = wp[((((cg * 2 + ct) * KK) + kk) * KB + kb) * 64 + lane];
    const float bv0 = bias[cg * 32 + colr], bv1 = bias[cg * 32 + 16 + colr];
    const int t0 = wg ? 3 : 0, t1 = wg ? 5 : 3;
    for (int t = t0; t < t1; ++t) {
        const int w = t * 16 + colr;
        f32x4 a0 = {0.f, 0.f, 0.f, 0.f}, a1 = {0.f, 0.f, 0.f, 0.f};
#pragma unroll
        for (int kk = 0; kk < KK; ++kk) {
            const int r8 = w + 8 - (KK - 1 - kk) * DIL;   // >= 0 always
            const int rb = r8 * RB, sx = r8 & 7;
#pragma unroll
            for (int kb = 0; kb < KB; ++kb) {
                const half8 a = *(const half8*)(inb + rb + ((((kb * 4 + quad) ^ sx)) << 4));
                a0 = MFMA16(a, wf[0][kk][kb], a0);
                a1 = MFMA16(a, wf[1][kk][kb], a1);
            }
        }
#pragma unroll
        for (int ct = 0; ct < 2; ++ct) {
            const float bv = ct ? bv1 : bv0;
            const int co = cg * 32 + ct * 16 + colr;
#pragma unroll
            for (int j = 0; j < 4; ++j) {
                const int r8o = t * 16 + quad * 4 + j + 8;
                char* p = outb + r8o * 256 + ((((co >> 3) ^ (r8o & 7))) << 4) + ((co & 7) << 1);
                float v = (ct ? a1[j] : a0[j]) + bv;
                if (RELU) v = fmaxf(v, 0.f);
                if (RES)  v = fmaxf(v + (float)*(const f16*)p, 0.f);
                *(f16*)p = (f16)v;
            }
        }
    }
}

extern "C" __global__ void __launch_bounds__(512, 2)
tcn_global(const float* __restrict__ src, const float* __restrict__ trg,
           f16* __restrict__ ws,
           const float* __restrict__ b01, const float* __restrict__ bd0,
           const float* __restrict__ b02, const float* __restrict__ b11,
           const float* __restrict__ b12, const float* __restrict__ b21,
           const float* __restrict__ b22)
{
    __shared__ __align__(16) char sX[88 * 128];
    __shared__ __align__(16) char sH1[88 * 256];
    __shared__ __align__(16) char sH2[88 * 256];
    const int tid = threadIdx.x;
    const int b = blockIdx.x >> 2, chunk = blockIdx.x & 3;
    const int u0 = chunk * 48;
    const float* srcb = src + (size_t)b * LSQ * 64;
    const float* trgb = trg + (size_t)b * TPQ * 64;

    for (int e = tid; e < 80 * 8; e += 512) {
        const int w = e >> 3, gg = e & 7;
        const int p = u0 - 28 + w;
        half8 v = {};
        if (p >= 0 && p < 192) {
            const float* ptr = (p < 168) ? (srcb + p * 64 + gg * 8) : (trgb + (p - 168) * 64 + gg * 8);
            const f4 f0 = *(const f4*)ptr; const f4 f1 = *(const f4*)(ptr + 4);
            v[0] = (f16)f0[0]; v[1] = (f16)f0[1]; v[2] = (f16)f0[2]; v[3] = (f16)f0[3];
            v[4] = (f16)f1[0]; v[5] = (f16)f1[1]; v[6] = (f16)f1[2]; v[7] = (f16)f1[3];
        }
        const int r8 = w + 8;
        *(half8*)(sX + r8 * 128 + ((gg ^ (r8 & 7)) << 4)) = v;
    }
    if (tid < 320) {
        const half8 z = {};
        if (tid < 64)       *(half8*)(sX + tid * 16) = z;
        else if (tid < 192) *(half8*)(sH1 + (tid - 64) * 16) = z;
        else                *(half8*)(sH2 + (tid - 192) * 16) = z;
    }
    __syncthreads();

    phaseA<64, 3, 1, 0, 1>(sX, sH1, ws, E0, b01, tid);
    phaseA<64, 1, 1, 0, 0>(sX, sH2, ws, ED, bd0, tid);
    __syncthreads();
    phaseA<128, 3, 1, 1, 1>(sH1, sH2, ws, E1, b02, tid);   // block0 out -> sH2
    __syncthreads();
    phaseA<128, 3, 2, 0, 1>(sH2, sH1, ws, E2, b11, tid);
    if (chunk == 0) {   // block0 out rows abs [0,40) -> G0
        for (int e = tid; e < 40 * 16; e += 512) {
            const int p = e >> 4, gc = e & 15, r8 = p + 36;
            const half8 v = *(const half8*)(sH2 + r8 * 256 + ((gc ^ (r8 & 7)) << 4));
            *(half8*)(ws + OG0 + (size_t)(b * 40 + p) * 128 + gc * 8) = v;
        }
    }
    __syncthreads();
    phaseA<128, 3, 2, 1, 1>(sH1, sH2, ws, E3, b12, tid);   // block1 out -> sH2
    __syncthreads();
    phaseA<128, 3, 4, 0, 1>(sH2, sH1, ws, E4, b21, tid);
    if (chunk == 0) {   // block1 out rows abs [0,48) -> G1
        for (int e = tid; e < 48 * 16; e += 512) {
            const int p = e >> 4, gc = e & 15, r8 = p + 36;
            const half8 v = *(const half8*)(sH2 + r8 * 256 + ((gc ^ (r8 & 7)) << 4));
            *(half8*)(ws + OG1 + (size_t)(b * 56 + p) * 128 + gc * 8) = v;
        }
    } else if (chunk == 1) {   // block1 out rows abs [48,56) -> G1
        for (int e = tid; e < 8 * 16; e += 512) {
            const int p = 48 + (e >> 4), gc = e & 15, r8 = p - 12;
            const half8 v = *(const half8*)(sH2 + r8 * 256 + ((gc ^ (r8 & 7)) << 4));
            *(half8*)(ws + OG1 + (size_t)(b * 56 + p) * 128 + gc * 8) = v;
        }
    }
    __syncthreads();
    phaseA<128, 3, 4, 1, 1>(sH1, sH2, ws, E5, b22, tid);   // block2 out -> sH2
    __syncthreads();
    for (int e = tid; e < 48 * 16; e += 512) {              // block2 out abs p>=32 -> G2
        const int pl = e >> 4, gc = e & 15, r8 = pl + 36;
        const int p = u0 + pl;
        if (p >= 32) {
            const half8 v = *(const half8*)(sH2 + r8 * 256 + ((gc ^ (r8 & 7)) << 4));
            *(half8*)(ws + OG2 + (size_t)(b * 160 + (p - 32)) * 128 + gc * 8) = v;
        }
    }
}

// ---------------- kernel BC: 4-wave blocks, 2 windows, co-32/wave ct-outer ----------------
template<int CIN, int KK, int DIL, int WPG, int SIN, int SOUT, int RES, int RELU, int NT>
__device__ __forceinline__ void bc_conv(
    const char* __restrict__ inb, char* __restrict__ outb, const char* __restrict__ zrp,
    const f16* __restrict__ ws, int eoff, const float* __restrict__ bias, int tid)
{
    constexpr int KB = CIN / 32;
    constexpr int RB = CIN * 2;
    const int lane = tid & 63, wid = tid >> 6;
    const int colr = lane & 15, quad = lane >> 4;
    const half8* __restrict__ wp = (const half8*)(ws + eoff);
#pragma unroll
    for (int ct = 0; ct < 2; ++ct) {
        half8 wf[KK][KB];
#pragma unroll
        for (int kk = 0; kk < KK; ++kk)
#pragma unroll
            for (int kb = 0; kb < KB; ++kb)
                wf[kk][kb] = wp[((((wid * 2 + ct) * KK) + kk) * KB + kb) * 64 + lane];
        const float bv = bias[wid * 32 + ct * 16 + colr];
#pragma unroll
        for (int t = 0; t < NT; ++t) {
            const int m = t * 16 + colr;
            const int g = m / WPG, w = m - g * WPG;
            f32x4 aA = {0.f, 0.f, 0.f, 0.f}, aB = {0.f, 0.f, 0.f, 0.f};
#pragma unroll
            for (int kk = 0; kk < KK; ++kk) {
                const int wq = w - (KK - 1 - kk) * DIL;
                const int row = g * SIN + wq;
                const char* rb = (wq < 0) ? zrp : (inb + row * RB);
                const int sx = (wq < 0) ? 0 : (row & 7);
#pragma unroll
                for (int kb = 0; kb < KB; ++kb) {
                    const half8 a = *(const half8*)(rb + ((((kb * 4 + quad) ^ sx)) << 4));
                    if (kb & 1) aB = MFMA16(a, wf[kk][kb], aB);
                    else        aA = MFMA16(a, wf[kk][kb], aA);
                }
            }
            const int co = wid * 32 + ct * 16 + colr;
#pragma unroll
            for (int j = 0; j < 4; ++j) {
                const int mo = t * 16 + quad * 4 + j;
                const int go = mo / WPG, wo = mo - go * WPG;
                if (go < 2) {
                    const int row = go * SOUT + wo;
                    char* p = outb + row * 256 + ((((co >> 3) ^ (row & 7))) << 4) + ((co & 7) << 1);
                    float v = aA[j] + aB[j] + bv;
                    if (RELU) v = fmaxf(v, 0.f);
                    if (RES)  v = fmaxf(v + (float)*(const f16*)p, 0.f);
                    *(f16*)p = (f16)v;
                }
            }
        }
    }
}

// P2: block0out = relu( relu(conv2b0(cb1)+b02) + convd(x)+bd0 ) -> BufB rows g*32+w, w<4
__device__ __forceinline__ void bc_p2(
    const char* __restrict__ bx, const char* __restrict__ cb1, char* __restrict__ outB,
    const char* __restrict__ zrp, const f16* __restrict__ ws,
    const float* __restrict__ b02, const float* __restrict__ bd0, int tid)
{
    const int lane = tid & 63, wid = tid >> 6;
    const int colr = lane & 15, quad = lane >> 4;
    const half8* __restrict__ wpA = (const half8*)(ws + E1);
    const half8* __restrict__ wpD = (const half8*)(ws + ED);
#pragma unroll
    for (int ct = 0; ct < 2; ++ct) {
        half8 wfa[3][4], wfd[2];
#pragma unroll
        for (int kk = 0; kk < 3; ++kk)
#pragma unroll
            for (int kb = 0; kb < 4; ++kb)
                wfa[kk][kb] = wpA[((((wid * 2 + ct) * 3) + kk) * 4 + kb) * 64 + lane];
#pragma unroll
        for (int kb = 0; kb < 2; ++kb)
            wfd[kb] = wpD[((wid * 2 + ct) * 2 + kb) * 64 + lane];
        const float ba = b02[wid * 32 + ct * 16 + colr];
        const float bd = bd0[wid * 32 + ct * 16 + colr];
        const int g = colr >> 2, w = colr & 3;
        f32x4 aA = {0.f,0.f,0.f,0.f}, aB = {0.f,0.f,0.f,0.f};
        f32x4 dA = {0.f,0.f,0.f,0.f}, dB = {0.f,0.f,0.f,0.f};
#pragma unroll
        for (int kk = 0; kk < 3; ++kk) {
            const int wq = w - (2 - kk);
            const int row = g * 4 + wq;
            const char* rb = (wq < 0) ? zrp : (cb1 + row * 256);
            const int sx = (wq < 0) ? 0 : (row & 7);
#pragma unroll
            for (int kb = 0; kb < 4; ++kb) {
                const half8 a = *(const half8*)(rb + ((((kb * 4 + quad) ^ sx)) << 4));
                if (kb & 1) aB = MFMA16(a, wfa[kk][kb], aB);
                else        aA = MFMA16(a, wfa[kk][kb], aA);
            }
        }
        {
            const int row = g * 4 + w;
            const char* rb = bx + row * 128;
            const int sx = row & 7;
            const half8 x0 = *(const half8*)(rb + (((0 * 4 + quad) ^ sx) << 4));
            const half8 x1 = *(const half8*)(rb + (((1 * 4 + quad) ^ sx) << 4));
            dA = MFMA16(x0, wfd[0], dA);
            dB = MFMA16(x1, wfd[1], dB);
        }
        const int co = wid * 32 + ct * 16 + colr;
#pragma unroll
        for (int j = 0; j < 4; ++j) {
            const int mo = quad * 4 + j;
            const int go = mo >> 2, wo = mo & 3;
            if (go < 2) {
                const int row = go * 32 + wo;
                char* p = outB + row * 256 + ((((co >> 3) ^ (row & 7))) << 4) + ((co & 7) << 1);
                const float ca = aA[j] + aB[j] + ba;
                const float cd = dA[j] + dB[j] + bd;
                *(f16*)p = (f16)fmaxf(fmaxf(ca, 0.f) + cd, 0.f);
            }
        }
    }
}

// dot of one half8 pair into f32 acc
__device__ __forceinline__ float dot8(half8 kv, half8 vq, float s) {
#if HAS_FDOT2
#pragma unroll
    for (int j2 = 0; j2 < 4; ++j2) {
        half2v a = {kv[2 * j2], kv[2 * j2 + 1]};
        half2v q = {vq[2 * j2], vq[2 * j2 + 1]};
        s = __builtin_amdgcn_fdot2(a, q, s, false);
    }
#else
#pragma unroll
    for (int j = 0; j < 8; ++j) s = fmaf((float)kv[j], (float)vq[j], s);
#endif
    return s;
}

extern "C" __global__ void __launch_bounds__(256, 2)
tcn_bdattn(const float* __restrict__ src, const f16* __restrict__ ws,
           const float* __restrict__ b01, const float* __restrict__ bd0,
           const float* __restrict__ b02, const float* __restrict__ b11,
           const float* __restrict__ b12, const float* __restrict__ b21,
           const float* __restrict__ b22,
           const float* __restrict__ h1w, const float* __restrict__ h1b,
           const float* __restrict__ h2w, const float* __restrict__ h2b,
           float* __restrict__ out)
{
    __shared__ __align__(16) char BufB[64 * 256];   // rows g*32+w
    __shared__ __align__(16) char BufC[64 * 256];   // rows g*32+w; start overlays scb1/sbx
    __shared__ __align__(16) char zr[256];
    __shared__ __align__(16) f16 qh[256];
    __shared__ float qf[256];
    __shared__ float sc[336];
    __shared__ float xs[336];
    __shared__ float cvp[2][2][128];
    char* scb1 = BufC;           // 8 rows x 256B (dead before conv1b1 writes BufC)
    char* sbx  = BufC + 2048;    // 8 rows x 128B

    const int tid = threadIdx.x, lane = tid & 63, wid = tid >> 6;
    const int n0 = blockIdx.x << 1;
    const int tp = n0 >> 7, b0 = n0 & 127;

    if (tid < 16) *(half8*)(zr + tid * 16) = half8{};
    if (tid < 64) {   // stage x rows [0,4) per window (2 win x 4 rows x 8 gran)
        const int g = tid >> 5, w = (tid >> 3) & 3, gg = tid & 7;
        const float* ptr = src + ((size_t)(b0 + g) * LSQ + (tp + w)) * 64 + gg * 8;
        const f4 f0 = *(const f4*)ptr; const f4 f1 = *(const f4*)(ptr + 4);
        half8 v;
        v[0] = (f16)f0[0]; v[1] = (f16)f0[1]; v[2] = (f16)f0[2]; v[3] = (f16)f0[3];
        v[4] = (f16)f1[0]; v[5] = (f16)f1[1]; v[6] = (f16)f1[2]; v[7] = (f16)f1[3];
        const int row = g * 4 + w;
        *(half8*)(sbx + row * 128 + ((gg ^ (row & 7)) << 4)) = v;
    }
    for (int e = tid; e < 384; e += 256) {   // G0 -> BufB rows g*32+[4,16)
        const int gc = e & 15, q = e >> 4;
        const int g = q / 12, pw = 4 + (q - g * 12);
        const half8 v = *(const half8*)(ws + OG0 + (size_t)((b0 + g) * 40 + (tp + pw)) * 128 + gc * 8);
        const int row = g * 32 + pw;
        *(half8*)(BufB + row * 256 + ((gc ^ (row & 7)) << 4)) = v;
    }
    for (int e = tid; e < 512; e += 256) {   // G1 -> BufB rows g*32+[16,32)
        const int gc = e & 15, q = e >> 4;
        const int g = q >> 4, pw = 16 + (q & 15);
        const half8 v = *(const half8*)(ws + OG1 + (size_t)((b0 + g) * 56 + (tp + pw)) * 128 + gc * 8);
        const int row = g * 32 + pw;
        *(half8*)(BufB + row * 256 + ((gc ^ (row & 7)) << 4)) = v;
    }
    if (tid < 32) {    // q (abs tp+168 -> G2 index tp+136) -> qh + qf
        const int g = tid >> 4, gc = tid & 15;
        const half8 v = *(const half8*)(ws + OG2 + ((size_t)(b0 + g) * 160 + tp + 136) * 128 + gc * 8);
        *(half8*)(qh + g * 128 + gc * 8) = v;
#pragma unroll
        for (int j = 0; j < 8; ++j) qf[g * 128 + gc * 8 + j] = (float)v[j];
    }
    __syncthreads();

    bc_conv<64, 3, 1, 4, 4, 4, 0, 1, 1>(sbx, scb1, zr, ws, E0, b01, tid);       // conv1b0 -> scb1
    __syncthreads();
    bc_p2(sbx, scb1, BufB, zr, ws, b02, bd0, tid);                               // block0 -> BufB w<4
    __syncthreads();
    bc_conv<128, 3, 2, 16, 32, 32, 0, 1, 2>(BufB, BufC, zr, ws, E2, b11, tid);  // conv1b1 -> BufC
    __syncthreads();
    bc_conv<128, 3, 2, 16, 32, 32, 1, 1, 2>(BufC, BufB, zr, ws, E3, b12, tid);  // block1 -> BufB w<16
    __syncthreads();
    bc_conv<128, 3, 4, 32, 32, 32, 0, 1, 4>(BufB, BufC, zr, ws, E4, b21, tid);  // conv1b2 -> BufC
    __syncthreads();
    bc_conv<128, 3, 4, 32, 32, 32, 1, 1, 4>(BufC, BufB, zr, ws, E5, b22, tid);  // block2 -> BufB w<32
    __syncthreads();

    // ---- attention: 2 waves per window (g = wid>>1, half h = wid&1) ----
    const int g = wid >> 1, h = wid & 1;
    const int b = b0 + g;
    const f16* __restrict__ g2r = ws + OG2 + ((size_t)b * 160 + tp - 32) * 128;  // +w*128 valid for w>=32
    const int wbase = h * 84;

    // scores for this wave's 84 positions
#pragma unroll
    for (int it = 0; it < 2; ++it) {
        const int w = wbase + it * 64 + lane;
        if (it == 0 || lane < 20) {
            float s = 0.f;
            if (w < 32) {
                const int row = g * 32 + w, sx = row & 7;
                const char* rb = BufB + row * 256;
#pragma unroll
                for (int gc = 0; gc < 16; ++gc) {
                    const half8 kv = *(const half8*)(rb + ((gc ^ sx) << 4));
                    const half8 vq = *(const half8*)(qh + g * 128 + gc * 8);
                    s = dot8(kv, vq, s);
                }
            } else {
                const half8* rb = (const half8*)(g2r + (size_t)w * 128);
#pragma unroll
                for (int gc = 0; gc < 16; ++gc) {
                    const half8 kv = rb[gc];
                    const half8 vq = *(const half8*)(qh + g * 128 + gc * 8);
                    s = dot8(kv, vq, s);
                }
            }
            sc[g * 168 + w] = s;
        }
    }
    __syncthreads();

    // rank-sort (desc, stable) — each wave ranks its 84 elements against all 168
    {
        const int w0i = wbase + lane;
        const int w1i = wbase + 64 + lane;
        const float v0 = sc[g * 168 + w0i];
        const float v1 = (lane < 20) ? sc[g * 168 + w1i] : 0.f;
        int r0 = 0, r1 = 0;
        for (int m2 = 0; m2 < LSQ; ++m2) {
            const float u = sc[g * 168 + m2];
            r0 += (u > v0) || ((u == v0) && (m2 < w0i));
            r1 += (u > v1) || ((u == v1) && (m2 < w1i));
        }
        xs[g * 168 + r0] = v0;
        if (lane < 20) xs[g * 168 + r1] = v1;
    }
    __syncthreads();

    // entmax threshold via shfl scan (computed redundantly in both waves of a window)
    const float mx = xs[g * 168];
    float tau;
    {
        const int i0 = lane * 3;
        const float a0 = (i0     < LSQ) ? (xs[g * 168 + i0]     - mx) * 0.5f : 0.f;
        const float a1 = (i0 + 1 < LSQ) ? (xs[g * 168 + i0 + 1] - mx) * 0.5f : 0.f;
        const float a2 = (i0 + 2 < LSQ) ? (xs[g * 168 + i0 + 2] - mx) * 0.5f : 0.f;
        const float s1 = a0, s2 = a0 + a1, s3 = a0 + a1 + a2;
        const float q1 = a0 * a0, q2 = q1 + a1 * a1, q3 = q2 + a2 * a2;
        float ts = s3, tq = q3;
#pragma unroll
        for (int o = 1; o < 64; o <<= 1) {
            const float us = __shfl_up(ts, o);
            const float uq = __shfl_up(tq, o);
            if (lane >= o) { ts += us; tq += uq; }
        }
        const float eS = ts - s3, eQ = tq - q3;
        float tau0v, tau1v, tau2v; int ind = 0;
#define TAUC(CIDX, CS, CQ, AV, TVAR) { \
        const float rho = (float)(i0 + CIDX + 1); \
        const float mean = (CS) / rho; \
        const float msq = (CQ) / rho; \
        const float ssv = rho * (msq - mean * mean); \
        float delta = (1.f - ssv) / rho; \
        delta = delta > 0.f ? delta : 0.f; \
        TVAR = mean - sqrtf(delta); \
        if (i0 + CIDX < LSQ && TVAR <= (AV)) ++ind; }
        TAUC(0, eS + s1, eQ + q1, a0, tau0v)
        TAUC(1, eS + s2, eQ + q2, a1, tau1v)
        TAUC(2, eS + s3, eQ + q3, a2, tau2v)
#undef TAUC
#pragma unroll
        for (int o = 32; o; o >>= 1) ind += __shfl_xor(ind, o);
        const int sm1 = ind - 1;
        const int srcl = sm1 / 3, c = sm1 - srcl * 3;
        const float tsel = (c == 0) ? tau0v : (c == 1) ? tau1v : tau2v;
        tau = __shfl(tsel, srcl);
    }

    // context partial over this wave's 84 positions (probs recomputed on the fly)
    {
        const int c0 = lane * 2;
        float cv0 = 0.f, cv1 = 0.f;
#pragma unroll 4
        for (int wi = 0; wi < 84; ++wi) {
            const int w = wbase + wi;
            float pz = (sc[g * 168 + w] - mx) * 0.5f - tau;
            pz = fmaxf(pz, 0.f);
            const float pw = pz * pz;
            float k0, k1;
            if (w < 32) {
                const int row = g * 32 + w, sx = row & 7;
                const char* p = BufB + row * 256 + (((c0 >> 3) ^ sx) << 4) + ((c0 & 7) << 1);
                k0 = (float)*(const f16*)p;
                k1 = (float)*(const f16*)(p + 2);
            } else {
                const f16* p = g2r + (size_t)w * 128 + c0;
                k0 = (float)p[0];
                k1 = (float)p[1];
            }
            cv0 = fmaf(pw, k0, cv0);
            cv1 = fmaf(pw, k1, cv1);
        }
        cvp[h][g][c0] = cv0;
        cvp[h][g][c0 + 1] = cv1;
    }
    __syncthreads();

    // heads (wave h==0 of each window)
    if (h == 0) {
        const int c0 = lane * 2;
        const float cva = cvp[0][g][c0]     + cvp[1][g][c0];
        const float cvb = cvp[0][g][c0 + 1] + cvp[1][g][c0 + 1];
        const float q0 = qf[g * 128 + c0], q1 = qf[g * 128 + c0 + 1];
        float s1 = h1w[c0] * cva + h1w[c0 + 1] * cvb + h1w[128 + c0] * q0 + h1w[128 + c0 + 1] * q1;
        float s2 = h2w[c0] * cva + h2w[c0 + 1] * cvb + h2w[128 + c0] * q0 + h2w[128 + c0 + 1] * q1;
#pragma unroll
        for (int o = 32; o; o >>= 1) {
            s1 += __shfl_xor(s1, o);
            s2 += __shfl_xor(s2, o);
        }
        if (lane == 0) {
            const float y1 = s1 + h1b[0];
            const float z = s2 + h2b[0];
            const float sp = (z > 0.f) ? (z + log1pf(expf(-z))) : log1pf(expf(z));
            out[b * TPQ + tp] = y1;
            out[BQ * TPQ + b * TPQ + tp] = sp;
        }
    }
}

extern "C" void kernel_launch(void* const* d_in, const int* in_sizes, int n_in,
                              void* d_out, int out_size, void* d_ws, size_t ws_size,
                              hipStream_t stream) {
    const float* src = (const float*)d_in[0];
    const float* trg = (const float*)d_in[1];
    const float* w01 = (const float*)d_in[2];
    const float* b01 = (const float*)d_in[3];
    const float* w02 = (const float*)d_in[4];
    const float* b02 = (const float*)d_in[5];
    const float* wd0 = (const float*)d_in[6];
    const float* bd0 = (const float*)d_in[7];
    const float* w11 = (const float*)d_in[8];
    const float* b11 = (const float*)d_in[9];
    const float* w12 = (const float*)d_in[10];
    const float* b12 = (const float*)d_in[11];
    const float* w21 = (const float*)d_in[12];
    const float* b21 = (const float*)d_in[13];
    const float* w22 = (const float*)d_in[14];
    const float* b22 = (const float*)d_in[15];
    const float* h1w = (const float*)d_in[16];
    const float* h1b = (const float*)d_in[17];
    const float* h2w = (const float*)d_in[18];
    const float* h2b = (const float*)d_in[19];
    f16* ws = (f16*)d_ws;

    pack_weights<<<dim3((WTOT + 255) / 256), dim3(256), 0, stream>>>(
        w01, wd0, w02, w11, w12, w21, w22, ws);

    tcn_global<<<dim3(BQ * 4), dim3(512), 0, stream>>>(
        src, trg, ws, b01, bd0, b02, b11, b12, b21, b22);

    tcn_bdattn<<<dim3(TPQ * BQ / 2), dim3(256), 0, stream>>>(
        src, ws, b01, bd0, b02, b11, b12, b21, b22,
        h1w, h1b, h2w, h2b, (float*)d_out);
}

// Round 9
// 161.463 us; speedup vs baseline: 1.0023x; 1.0023x over previous
//
#include <hip/hip_runtime.h>
#include <math.h>

typedef _Float16 f16;
typedef __attribute__((ext_vector_type(8))) _Float16 half8;
typedef __attribute__((ext_vector_type(2))) _Float16 half2v;
typedef __attribute__((ext_vector_type(4))) float f32x4;
typedef __attribute__((ext_vector_type(4))) float f4;

#define TPQ 24
#define BQ 128
#define LSQ 168

#if __has_builtin(__builtin_amdgcn_fdot2)
#define HAS_FDOT2 1
#else
#define HAS_FDOT2 0
#endif

// ws element offsets (fp16 elements)
#define E0 0        /* w01 frags */
#define ED 24576    /* wd0 */
#define E1 32768    /* w02 */
#define E2 81920    /* w11 */
#define E3 131072   /* w12 */
#define E4 180224   /* w21 */
#define E5 229376   /* w22 */
#define WTOT 278528
#define OG2 278528                       /* block2 out: [128][160][128], abs pos p-32 */
#define OG1 2899968                      /* block1 out: [128][56][128]  */
#define OG0 3817472                      /* block0 out: [128][40][128]  */
/* end: 4472832 el = 8.95 MB */

#define MFMA16(a, b, c) __builtin_amdgcn_mfma_f32_16x16x32_f16((a), (b), (c), 0, 0, 0)

// ---------------- weight fragment packing ----------------
extern "C" __global__ void pack_weights(
    const float* __restrict__ w01, const float* __restrict__ wd0,
    const float* __restrict__ w02, const float* __restrict__ w11,
    const float* __restrict__ w12, const float* __restrict__ w21,
    const float* __restrict__ w22, f16* __restrict__ ws)
{
    int e = blockIdx.x * 256 + threadIdx.x;
    if (e >= WTOT) return;
    const float* W; int CIN, KK, el;
    if (e < ED) { W = w01; CIN = 64; KK = 3; el = e; }
    else if (e < E1) { W = wd0; CIN = 64; KK = 1; el = e - ED; }
    else {
        int c = (e - E1) / 49152; el = (e - E1) % 49152; CIN = 128; KK = 3;
        W = (c == 0) ? w02 : (c == 1) ? w11 : (c == 2) ? w12 : (c == 3) ? w21 : w22;
    }
    const int KB = CIN / 32;
    const int frag = el >> 9, wi = el & 511, lane = wi >> 3, i = wi & 7;
    const int coT = frag / (KK * KB), rem = frag % (KK * KB);
    const int kk = rem / KB, kb = rem % KB;
    const int co = coT * 16 + (lane & 15);
    const int ci = kb * 32 + (lane >> 4) * 8 + i;
    ws[e] = (f16)W[(co * CIN + ci) * KK + kk];
}

// ---------------- kernel A: global TCN over full srctrg ----------------
template<int CIN, int KK, int DIL, int RES, int RELU>
__device__ __forceinline__ void phaseA(
    const char* __restrict__ inb, char* __restrict__ outb,
    const f16* __restrict__ ws, int eoff, const float* __restrict__ bias, int tid)
{
    constexpr int KB = CIN / 32;
    constexpr int RB = CIN * 2;
    const int lane = tid & 63, wid = tid >> 6;
    const int cg = wid & 3, wg = wid >> 2;
    const int colr = lane & 15, quad = lane >> 4;
    const half8* __restrict__ wp = (const half8*)(ws + eoff);
    half8 wf[2][KK][KB];
#pragma unroll
    for (int ct = 0; ct < 2; ++ct)
#pragma unroll
        for (int kk = 0; kk < KK; ++kk)
#pragma unroll
            for (int kb = 0; kb < KB; ++kb)
                wf[ct][kk][kb] = wp[((((cg * 2 + ct) * KK) + kk) * KB + kb) * 64 + lane];
    const float bv0 = bias[cg * 32 + colr], bv1 = bias[cg * 32 + 16 + colr];
    const int t0 = wg ? 3 : 0, t1 = wg ? 5 : 3;
    for (int t = t0; t < t1; ++t) {
        const int w = t * 16 + colr;
        f32x4 a0 = {0.f, 0.f, 0.f, 0.f}, a1 = {0.f, 0.f, 0.f, 0.f};
#pragma unroll
        for (int kk = 0; kk < KK; ++kk) {
            const int r8 = w + 8 - (KK - 1 - kk) * DIL;   // >= 0 always
            const int rb = r8 * RB, sx = r8 & 7;
#pragma unroll
            for (int kb = 0; kb < KB; ++kb) {
                const half8 a = *(const half8*)(inb + rb + ((((kb * 4 + quad) ^ sx)) << 4));
                a0 = MFMA16(a, wf[0][kk][kb], a0);
                a1 = MFMA16(a, wf[1][kk][kb], a1);
            }
        }
#pragma unroll
        for (int ct = 0; ct < 2; ++ct) {
            const float bv = ct ? bv1 : bv0;
            const int co = cg * 32 + ct * 16 + colr;
#pragma unroll
            for (int j = 0; j < 4; ++j) {
                const int r8o = t * 16 + quad * 4 + j + 8;
                char* p = outb + r8o * 256 + ((((co >> 3) ^ (r8o & 7))) << 4) + ((co & 7) << 1);
                float v = (ct ? a1[j] : a0[j]) + bv;
                if (RELU) v = fmaxf(v, 0.f);
                if (RES)  v = fmaxf(v + (float)*(const f16*)p, 0.f);
                *(f16*)p = (f16)v;
            }
        }
    }
}

extern "C" __global__ void __launch_bounds__(512, 2)
tcn_global(const float* __restrict__ src, const float* __restrict__ trg,
           f16* __restrict__ ws,
           const float* __restrict__ b01, const float* __restrict__ bd0,
           const float* __restrict__ b02, const float* __restrict__ b11,
           const float* __restrict__ b12, const float* __restrict__ b21,
           const float* __restrict__ b22)
{
    __shared__ __align__(16) char sX[88 * 128];
    __shared__ __align__(16) char sH1[88 * 256];
    __shared__ __align__(16) char sH2[88 * 256];
    const int tid = threadIdx.x;
    const int b = blockIdx.x >> 2, chunk = blockIdx.x & 3;
    const int u0 = chunk * 48;
    const float* srcb = src + (size_t)b * LSQ * 64;
    const float* trgb = trg + (size_t)b * TPQ * 64;

    for (int e = tid; e < 80 * 8; e += 512) {
        const int w = e >> 3, gg = e & 7;
        const int p = u0 - 28 + w;
        half8 v = {};
        if (p >= 0 && p < 192) {
            const float* ptr = (p < 168) ? (srcb + p * 64 + gg * 8) : (trgb + (p - 168) * 64 + gg * 8);
            const f4 f0 = *(const f4*)ptr; const f4 f1 = *(const f4*)(ptr + 4);
            v[0] = (f16)f0[0]; v[1] = (f16)f0[1]; v[2] = (f16)f0[2]; v[3] = (f16)f0[3];
            v[4] = (f16)f1[0]; v[5] = (f16)f1[1]; v[6] = (f16)f1[2]; v[7] = (f16)f1[3];
        }
        const int r8 = w + 8;
        *(half8*)(sX + r8 * 128 + ((gg ^ (r8 & 7)) << 4)) = v;
    }
    if (tid < 320) {
        const half8 z = {};
        if (tid < 64)       *(half8*)(sX + tid * 16) = z;
        else if (tid < 192) *(half8*)(sH1 + (tid - 64) * 16) = z;
        else                *(half8*)(sH2 + (tid - 192) * 16) = z;
    }
    __syncthreads();

    phaseA<64, 3, 1, 0, 1>(sX, sH1, ws, E0, b01, tid);
    phaseA<64, 1, 1, 0, 0>(sX, sH2, ws, ED, bd0, tid);
    __syncthreads();
    phaseA<128, 3, 1, 1, 1>(sH1, sH2, ws, E1, b02, tid);   // block0 out -> sH2
    __syncthreads();
    phaseA<128, 3, 2, 0, 1>(sH2, sH1, ws, E2, b11, tid);
    if (chunk == 0) {   // block0 out rows abs [0,40) -> G0
        for (int e = tid; e < 40 * 16; e += 512) {
            const int p = e >> 4, gc = e & 15, r8 = p + 36;
            const half8 v = *(const half8*)(sH2 + r8 * 256 + ((gc ^ (r8 & 7)) << 4));
            *(half8*)(ws + OG0 + (size_t)(b * 40 + p) * 128 + gc * 8) = v;
        }
    }
    __syncthreads();
    phaseA<128, 3, 2, 1, 1>(sH1, sH2, ws, E3, b12, tid);   // block1 out -> sH2
    __syncthreads();
    phaseA<128, 3, 4, 0, 1>(sH2, sH1, ws, E4, b21, tid);
    if (chunk == 0) {   // block1 out rows abs [0,48) -> G1
        for (int e = tid; e < 48 * 16; e += 512) {
            const int p = e >> 4, gc = e & 15, r8 = p + 36;
            const half8 v = *(const half8*)(sH2 + r8 * 256 + ((gc ^ (r8 & 7)) << 4));
            *(half8*)(ws + OG1 + (size_t)(b * 56 + p) * 128 + gc * 8) = v;
        }
    } else if (chunk == 1) {   // block1 out rows abs [48,56) -> G1
        for (int e = tid; e < 8 * 16; e += 512) {
            const int p = 48 + (e >> 4), gc = e & 15, r8 = p - 12;
            const half8 v = *(const half8*)(sH2 + r8 * 256 + ((gc ^ (r8 & 7)) << 4));
            *(half8*)(ws + OG1 + (size_t)(b * 56 + p) * 128 + gc * 8) = v;
        }
    }
    __syncthreads();
    phaseA<128, 3, 4, 1, 1>(sH1, sH2, ws, E5, b22, tid);   // block2 out -> sH2
    __syncthreads();
    for (int e = tid; e < 48 * 16; e += 512) {              // block2 out abs p>=32 -> G2
        const int pl = e >> 4, gc = e & 15, r8 = pl + 36;
        const int p = u0 + pl;
        if (p >= 32) {
            const half8 v = *(const half8*)(sH2 + r8 * 256 + ((gc ^ (r8 & 7)) << 4));
            *(half8*)(ws + OG2 + (size_t)(b * 160 + (p - 32)) * 128 + gc * 8) = v;
        }
    }
}

// ---------------- kernel BC: 4-wave blocks, 2 windows, co-32/wave ct-outer ----------------
template<int CIN, int KK, int DIL, int WPG, int SIN, int SOUT, int RES, int RELU, int NT>
__device__ __forceinline__ void bc_conv(
    const char* __restrict__ inb, char* __restrict__ outb, const char* __restrict__ zrp,
    const f16* __restrict__ ws, int eoff, const float* __restrict__ bias, int tid)
{
    constexpr int KB = CIN / 32;
    constexpr int RB = CIN * 2;
    const int lane = tid & 63, wid = tid >> 6;
    const int colr = lane & 15, quad = lane >> 4;
    const half8* __restrict__ wp = (const half8*)(ws + eoff);
#pragma unroll
    for (int ct = 0; ct < 2; ++ct) {
        half8 wf[KK][KB];
#pragma unroll
        for (int kk = 0; kk < KK; ++kk)
#pragma unroll
            for (int kb = 0; kb < KB; ++kb)
                wf[kk][kb] = wp[((((wid * 2 + ct) * KK) + kk) * KB + kb) * 64 + lane];
        const float bv = bias[wid * 32 + ct * 16 + colr];
#pragma unroll
        for (int t = 0; t < NT; ++t) {
            const int m = t * 16 + colr;
            const int g = m / WPG, w = m - g * WPG;
            f32x4 aA = {0.f, 0.f, 0.f, 0.f}, aB = {0.f, 0.f, 0.f, 0.f};
#pragma unroll
            for (int kk = 0; kk < KK; ++kk) {
                const int wq = w - (KK - 1 - kk) * DIL;
                const int row = g * SIN + wq;
                const char* rb = (wq < 0) ? zrp : (inb + row * RB);
                const int sx = (wq < 0) ? 0 : (row & 7);
#pragma unroll
                for (int kb = 0; kb < KB; ++kb) {
                    const half8 a = *(const half8*)(rb + ((((kb * 4 + quad) ^ sx)) << 4));
                    if (kb & 1) aB = MFMA16(a, wf[kk][kb], aB);
                    else        aA = MFMA16(a, wf[kk][kb], aA);
                }
            }
            const int co = wid * 32 + ct * 16 + colr;
#pragma unroll
            for (int j = 0; j < 4; ++j) {
                const int mo = t * 16 + quad * 4 + j;
                const int go = mo / WPG, wo = mo - go * WPG;
                if (go < 2) {
                    const int row = go * SOUT + wo;
                    char* p = outb + row * 256 + ((((co >> 3) ^ (row & 7))) << 4) + ((co & 7) << 1);
                    float v = aA[j] + aB[j] + bv;
                    if (RELU) v = fmaxf(v, 0.f);
                    if (RES)  v = fmaxf(v + (float)*(const f16*)p, 0.f);
                    *(f16*)p = (f16)v;
                }
            }
        }
    }
}

// P2: block0out = relu( relu(conv2b0(cb1)+b02) + convd(x)+bd0 ) -> BufB rows g*32+w, w<4
__device__ __forceinline__ void bc_p2(
    const char* __restrict__ bx, const char* __restrict__ cb1, char* __restrict__ outB,
    const char* __restrict__ zrp, const f16* __restrict__ ws,
    const float* __restrict__ b02, const float* __restrict__ bd0, int tid)
{
    const int lane = tid & 63, wid = tid >> 6;
    const int colr = lane & 15, quad = lane >> 4;
    const half8* __restrict__ wpA = (const half8*)(ws + E1);
    const half8* __restrict__ wpD = (const half8*)(ws + ED);
#pragma unroll
    for (int ct = 0; ct < 2; ++ct) {
        half8 wfa[3][4], wfd[2];
#pragma unroll
        for (int kk = 0; kk < 3; ++kk)
#pragma unroll
            for (int kb = 0; kb < 4; ++kb)
                wfa[kk][kb] = wpA[((((wid * 2 + ct) * 3) + kk) * 4 + kb) * 64 + lane];
#pragma unroll
        for (int kb = 0; kb < 2; ++kb)
            wfd[kb] = wpD[((wid * 2 + ct) * 2 + kb) * 64 + lane];
        const float ba = b02[wid * 32 + ct * 16 + colr];
        const float bd = bd0[wid * 32 + ct * 16 + colr];
        const int g = colr >> 2, w = colr & 3;
        f32x4 aA = {0.f,0.f,0.f,0.f}, aB = {0.f,0.f,0.f,0.f};
        f32x4 dA = {0.f,0.f,0.f,0.f}, dB = {0.f,0.f,0.f,0.f};
#pragma unroll
        for (int kk = 0; kk < 3; ++kk) {
            const int wq = w - (2 - kk);
            const int row = g * 4 + wq;
            const char* rb = (wq < 0) ? zrp : (cb1 + row * 256);
            const int sx = (wq < 0) ? 0 : (row & 7);
#pragma unroll
            for (int kb = 0; kb < 4; ++kb) {
                const half8 a = *(const half8*)(rb + ((((kb * 4 + quad) ^ sx)) << 4));
                if (kb & 1) aB = MFMA16(a, wfa[kk][kb], aB);
                else        aA = MFMA16(a, wfa[kk][kb], aA);
            }
        }
        {
            const int row = g * 4 + w;
            const char* rb = bx + row * 128;
            const int sx = row & 7;
            const half8 x0 = *(const half8*)(rb + (((0 * 4 + quad) ^ sx) << 4));
            const half8 x1 = *(const half8*)(rb + (((1 * 4 + quad) ^ sx) << 4));
            dA = MFMA16(x0, wfd[0], dA);
            dB = MFMA16(x1, wfd[1], dB);
        }
        const int co = wid * 32 + ct * 16 + colr;
#pragma unroll
        for (int j = 0; j < 4; ++j) {
            const int mo = quad * 4 + j;
            const int go = mo >> 2, wo = mo & 3;
            if (go < 2) {
                const int row = go * 32 + wo;
                char* p = outB + row * 256 + ((((co >> 3) ^ (row & 7))) << 4) + ((co & 7) << 1);
                const float ca = aA[j] + aB[j] + ba;
                const float cd = dA[j] + dB[j] + bd;
                *(f16*)p = (f16)fmaxf(fmaxf(ca, 0.f) + cd, 0.f);
            }
        }
    }
}

// dot of one half8 pair into f32 acc
__device__ __forceinline__ float dot8(half8 kv, half8 vq, float s) {
#if HAS_FDOT2
#pragma unroll
    for (int j2 = 0; j2 < 4; ++j2) {
        half2v a = {kv[2 * j2], kv[2 * j2 + 1]};
        half2v q = {vq[2 * j2], vq[2 * j2 + 1]};
        s = __builtin_amdgcn_fdot2(a, q, s, false);
    }
#else
#pragma unroll
    for (int j = 0; j < 8; ++j) s = fmaf((float)kv[j], (float)vq[j], s);
#endif
    return s;
}

extern "C" __global__ void __launch_bounds__(256, 2)
tcn_bdattn(const float* __restrict__ src, const f16* __restrict__ ws,
           const float* __restrict__ b01, const float* __restrict__ bd0,
           const float* __restrict__ b02, const float* __restrict__ b11,
           const float* __restrict__ b12, const float* __restrict__ b21,
           const float* __restrict__ b22,
           const float* __restrict__ h1w, const float* __restrict__ h1b,
           const float* __restrict__ h2w, const float* __restrict__ h2b,
           float* __restrict__ out)
{
    __shared__ __align__(16) char BufB[64 * 256];   // rows g*32+w
    __shared__ __align__(16) char BufC[64 * 256];   // rows g*32+w; start overlays scb1/sbx
    __shared__ __align__(16) char zr[256];
    __shared__ __align__(16) f16 qh[256];
    __shared__ float qf[256];
    __shared__ float sc[336];
    __shared__ float xs[336];
    __shared__ float cvp[2][2][128];
    char* scb1 = BufC;           // 8 rows x 256B (dead before conv1b1 writes BufC)
    char* sbx  = BufC + 2048;    // 8 rows x 128B

    const int tid = threadIdx.x, lane = tid & 63, wid = tid >> 6;
    const int n0 = blockIdx.x << 1;
    const int tp = n0 >> 7, b0 = n0 & 127;

    if (tid < 16) *(half8*)(zr + tid * 16) = half8{};
    if (tid < 64) {   // stage x rows [0,4) per window (2 win x 4 rows x 8 gran)
        const int g = tid >> 5, w = (tid >> 3) & 3, gg = tid & 7;
        const float* ptr = src + ((size_t)(b0 + g) * LSQ + (tp + w)) * 64 + gg * 8;
        const f4 f0 = *(const f4*)ptr; const f4 f1 = *(const f4*)(ptr + 4);
        half8 v;
        v[0] = (f16)f0[0]; v[1] = (f16)f0[1]; v[2] = (f16)f0[2]; v[3] = (f16)f0[3];
        v[4] = (f16)f1[0]; v[5] = (f16)f1[1]; v[6] = (f16)f1[2]; v[7] = (f16)f1[3];
        const int row = g * 4 + w;
        *(half8*)(sbx + row * 128 + ((gg ^ (row & 7)) << 4)) = v;
    }
    for (int e = tid; e < 384; e += 256) {   // G0 -> BufB rows g*32+[4,16)
        const int gc = e & 15, q = e >> 4;
        const int g = q / 12, pw = 4 + (q - g * 12);
        const half8 v = *(const half8*)(ws + OG0 + (size_t)((b0 + g) * 40 + (tp + pw)) * 128 + gc * 8);
        const int row = g * 32 + pw;
        *(half8*)(BufB + row * 256 + ((gc ^ (row & 7)) << 4)) = v;
    }
    for (int e = tid; e < 512; e += 256) {   // G1 -> BufB rows g*32+[16,32)
        const int gc = e & 15, q = e >> 4;
        const int g = q >> 4, pw = 16 + (q & 15);
        const half8 v = *(const half8*)(ws + OG1 + (size_t)((b0 + g) * 56 + (tp + pw)) * 128 + gc * 8);
        const int row = g * 32 + pw;
        *(half8*)(BufB + row * 256 + ((gc ^ (row & 7)) << 4)) = v;
    }
    if (tid < 32) {    // q (abs tp+168 -> G2 index tp+136) -> qh + qf
        const int g = tid >> 4, gc = tid & 15;
        const half8 v = *(const half8*)(ws + OG2 + ((size_t)(b0 + g) * 160 + tp + 136) * 128 + gc * 8);
        *(half8*)(qh + g * 128 + gc * 8) = v;
#pragma unroll
        for (int j = 0; j < 8; ++j) qf[g * 128 + gc * 8 + j] = (float)v[j];
    }
    __syncthreads();

    bc_conv<64, 3, 1, 4, 4, 4, 0, 1, 1>(sbx, scb1, zr, ws, E0, b01, tid);       // conv1b0 -> scb1
    __syncthreads();
    bc_p2(sbx, scb1, BufB, zr, ws, b02, bd0, tid);                               // block0 -> BufB w<4
    __syncthreads();
    bc_conv<128, 3, 2, 16, 32, 32, 0, 1, 2>(BufB, BufC, zr, ws, E2, b11, tid);  // conv1b1 -> BufC
    __syncthreads();
    bc_conv<128, 3, 2, 16, 32, 32, 1, 1, 2>(BufC, BufB, zr, ws, E3, b12, tid);  // block1 -> BufB w<16
    __syncthreads();
    bc_conv<128, 3, 4, 32, 32, 32, 0, 1, 4>(BufB, BufC, zr, ws, E4, b21, tid);  // conv1b2 -> BufC
    __syncthreads();
    bc_conv<128, 3, 4, 32, 32, 32, 1, 1, 4>(BufC, BufB, zr, ws, E5, b22, tid);  // block2 -> BufB w<32
    __syncthreads();

    // ---- attention: 2 waves per window (g = wid>>1, half h = wid&1) ----
    const int g = wid >> 1, h = wid & 1;
    const int b = b0 + g;
    const f16* __restrict__ g2r = ws + OG2 + ((size_t)b * 160 + tp - 32) * 128;  // +w*128 valid for w>=32
    const int wbase = h * 84;

    // scores for this wave's 84 positions
#pragma unroll
    for (int it = 0; it < 2; ++it) {
        const int w = wbase + it * 64 + lane;
        if (it == 0 || lane < 20) {
            float s = 0.f;
            if (w < 32) {
                const int row = g * 32 + w, sx = row & 7;
                const char* rb = BufB + row * 256;
#pragma unroll
                for (int gc = 0; gc < 16; ++gc) {
                    const half8 kv = *(const half8*)(rb + ((gc ^ sx) << 4));
                    const half8 vq = *(const half8*)(qh + g * 128 + gc * 8);
                    s = dot8(kv, vq, s);
                }
            } else {
                const half8* rb = (const half8*)(g2r + (size_t)w * 128);
#pragma unroll
                for (int gc = 0; gc < 16; ++gc) {
                    const half8 kv = rb[gc];
                    const half8 vq = *(const half8*)(qh + g * 128 + gc * 8);
                    s = dot8(kv, vq, s);
                }
            }
            sc[g * 168 + w] = s;
        }
    }
    __syncthreads();

    // rank-sort (desc, stable) — each wave ranks its 84 elements against all 168
    {
        const int w0i = wbase + lane;
        const int w1i = wbase + 64 + lane;
        const float v0 = sc[g * 168 + w0i];
        const float v1 = (lane < 20) ? sc[g * 168 + w1i] : 0.f;
        int r0 = 0, r1 = 0;
        for (int m2 = 0; m2 < LSQ; ++m2) {
            const float u = sc[g * 168 + m2];
            r0 += (u > v0) || ((u == v0) && (m2 < w0i));
            r1 += (u > v1) || ((u == v1) && (m2 < w1i));
        }
        xs[g * 168 + r0] = v0;
        if (lane < 20) xs[g * 168 + r1] = v1;
    }
    __syncthreads();

    // entmax threshold via shfl scan (computed redundantly in both waves of a window)
    const float mx = xs[g * 168];
    float tau;
    {
        const int i0 = lane * 3;
        const float a0 = (i0     < LSQ) ? (xs[g * 168 + i0]     - mx) * 0.5f : 0.f;
        const float a1 = (i0 + 1 < LSQ) ? (xs[g * 168 + i0 + 1] - mx) * 0.5f : 0.f;
        const float a2 = (i0 + 2 < LSQ) ? (xs[g * 168 + i0 + 2] - mx) * 0.5f : 0.f;
        const float s1 = a0, s2 = a0 + a1, s3 = a0 + a1 + a2;
        const float q1 = a0 * a0, q2 = q1 + a1 * a1, q3 = q2 + a2 * a2;
        float ts = s3, tq = q3;
#pragma unroll
        for (int o = 1; o < 64; o <<= 1) {
            const float us = __shfl_up(ts, o);
            const float uq = __shfl_up(tq, o);
            if (lane >= o) { ts += us; tq += uq; }
        }
        const float eS = ts - s3, eQ = tq - q3;
        float tau0v, tau1v, tau2v; int ind = 0;
#define TAUC(CIDX, CS, CQ, AV, TVAR) { \
        const float rho = (float)(i0 + CIDX + 1); \
        const float mean = (CS) / rho; \
        const float msq = (CQ) / rho; \
        const float ssv = rho * (msq - mean * mean); \
        float delta = (1.f - ssv) / rho; \
        delta = delta > 0.f ? delta : 0.f; \
        TVAR = mean - sqrtf(delta); \
        if (i0 + CIDX < LSQ && TVAR <= (AV)) ++ind; }
        TAUC(0, eS + s1, eQ + q1, a0, tau0v)
        TAUC(1, eS + s2, eQ + q2, a1, tau1v)
        TAUC(2, eS + s3, eQ + q3, a2, tau2v)
#undef TAUC
#pragma unroll
        for (int o = 32; o; o >>= 1) ind += __shfl_xor(ind, o);
        const int sm1 = ind - 1;
        const int srcl = sm1 / 3, c = sm1 - srcl * 3;
        const float tsel = (c == 0) ? tau0v : (c == 1) ? tau1v : tau2v;
        tau = __shfl(tsel, srcl);
    }

    // context partial over this wave's 84 positions (probs recomputed on the fly)
    {
        const int c0 = lane * 2;
        float cv0 = 0.f, cv1 = 0.f;
#pragma unroll 4
        for (int wi = 0; wi < 84; ++wi) {
            const int w = wbase + wi;
            float pz = (sc[g * 168 + w] - mx) * 0.5f - tau;
            pz = fmaxf(pz, 0.f);
            const float pw = pz * pz;
            float k0, k1;
            if (w < 32) {
                const int row = g * 32 + w, sx = row & 7;
                const char* p = BufB + row * 256 + (((c0 >> 3) ^ sx) << 4) + ((c0 & 7) << 1);
                k0 = (float)*(const f16*)p;
                k1 = (float)*(const f16*)(p + 2);
            } else {
                const f16* p = g2r + (size_t)w * 128 + c0;
                k0 = (float)p[0];
                k1 = (float)p[1];
            }
            cv0 = fmaf(pw, k0, cv0);
            cv1 = fmaf(pw, k1, cv1);
        }
        cvp[h][g][c0] = cv0;
        cvp[h][g][c0 + 1] = cv1;
    }
    __syncthreads();

    // heads (wave h==0 of each window)
    if (h == 0) {
        const int c0 = lane * 2;
        const float cva = cvp[0][g][c0]     + cvp[1][g][c0];
        const float cvb = cvp[0][g][c0 + 1] + cvp[1][g][c0 + 1];
        const float q0 = qf[g * 128 + c0], q1 = qf[g * 128 + c0 + 1];
        float s1 = h1w[c0] * cva + h1w[c0 + 1] * cvb + h1w[128 + c0] * q0 + h1w[128 + c0 + 1] * q1;
        float s2 = h2w[c0] * cva + h2w[c0 + 1] * cvb + h2w[128 + c0] * q0 + h2w[128 + c0 + 1] * q1;
#pragma unroll
        for (int o = 32; o; o >>= 1) {
            s1 += __shfl_xor(s1, o);
            s2 += __shfl_xor(s2, o);
        }
        if (lane == 0) {
            const float y1 = s1 + h1b[0];
            const float z = s2 + h2b[0];
            const float sp = (z > 0.f) ? (z + log1pf(expf(-z))) : log1pf(expf(z));
            out[b * TPQ + tp] = y1;
            out[BQ * TPQ + b * TPQ + tp] = sp;
        }
    }
}

extern "C" void kernel_launch(void* const* d_in, const int* in_sizes, int n_in,
                              void* d_out, int out_size, void* d_ws, size_t ws_size,
                              hipStream_t stream) {
    const float* src = (const float*)d_in[0];
    const float* trg = (const float*)d_in[1];
    const float* w01 = (const float*)d_in[2];
    const float* b01 = (const float*)d_in[3];
    const float* w02 = (const float*)d_in[4];
    const float* b02 = (const float*)d_in[5];
    const float* wd0 = (const float*)d_in[6];
    const float* bd0 = (const float*)d_in[7];
    const float* w11 = (const float*)d_in[8];
    const float* b11 = (const float*)d_in[9];
    const float* w12 = (const float*)d_in[10];
    const float* b12 = (const float*)d_in[11];
    const float* w21 = (const float*)d_in[12];
    const float* b21 = (const float*)d_in[13];
    const float* w22 = (const float*)d_in[14];
    const float* b22 = (const float*)d_in[15];
    const float* h1w = (const float*)d_in[16];
    const float* h1b = (const float*)d_in[17];
    const float* h2w = (const float*)d_in[18];
    const float* h2b = (const float*)d_in[19];
    f16* ws = (f16*)d_ws;

    pack_weights<<<dim3((WTOT + 255) / 256), dim3(256), 0, stream>>>(
        w01, wd0, w02, w11, w12, w21, w22, ws);

    tcn_global<<<dim3(BQ * 4), dim3(512), 0, stream>>>(
        src, trg, ws, b01, bd0, b02, b11, b12, b21, b22);

    tcn_bdattn<<<dim3(TPQ * BQ / 2), dim3(256), 0, stream>>>(
        src, ws, b01, bd0, b02, b11, b12, b21, b22,
        h1w, h1b, h2w, h2b, (float*)d_out);
}

// Round 10
// 161.349 us; speedup vs baseline: 1.0030x; 1.0007x over previous
//
#include <hip/hip_runtime.h>
#include <math.h>

typedef _Float16 f16;
typedef __attribute__((ext_vector_type(8))) _Float16 half8;
typedef __attribute__((ext_vector_type(2))) _Float16 half2v;
typedef __attribute__((ext_vector_type(4))) float f32x4;
typedef __attribute__((ext_vector_type(4))) float f4;

#define TPQ 24
#define BQ 128
#define LSQ 168

#if __has_builtin(__builtin_amdgcn_fdot2)
#define HAS_FDOT2 1
#else
#define HAS_FDOT2 0
#endif

// ws element offsets (fp16 elements)
#define E0 0        /* w01 frags */
#define ED 24576    /* wd0 */
#define E1 32768    /* w02 */
#define E2 81920    /* w11 */
#define E3 131072   /* w12 */
#define E4 180224   /* w21 */
#define E5 229376   /* w22 */
#define WTOT 278528
#define OG2 278528                       /* block2 out: [128][160][128], abs pos p-32 */
#define OG1 2899968                      /* block1 out: [128][56][128]  */
#define OG0 3817472                      /* block0 out: [128][40][128]  */
/* end: 4472832 el = 8.95 MB */

#define MFMA16(a, b, c) __builtin_amdgcn_mfma_f32_16x16x32_f16((a), (b), (c), 0, 0, 0)

// ---------------- weight fragment packing ----------------
extern "C" __global__ void pack_weights(
    const float* __restrict__ w01, const float* __restrict__ wd0,
    const float* __restrict__ w02, const float* __restrict__ w11,
    const float* __restrict__ w12, const float* __restrict__ w21,
    const float* __restrict__ w22, f16* __restrict__ ws)
{
    int e = blockIdx.x * 256 + threadIdx.x;
    if (e >= WTOT) return;
    const float* W; int CIN, KK, el;
    if (e < ED) { W = w01; CIN = 64; KK = 3; el = e; }
    else if (e < E1) { W = wd0; CIN = 64; KK = 1; el = e - ED; }
    else {
        int c = (e - E1) / 49152; el = (e - E1) % 49152; CIN = 128; KK = 3;
        W = (c == 0) ? w02 : (c == 1) ? w11 : (c == 2) ? w12 : (c == 3) ? w21 : w22;
    }
    const int KB = CIN / 32;
    const int frag = el >> 9, wi = el & 511, lane = wi >> 3, i = wi & 7;
    const int coT = frag / (KK * KB), rem = frag % (KK * KB);
    const int kk = rem / KB, kb = rem % KB;
    const int co = coT * 16 + (lane & 15);
    const int ci = kb * 32 + (lane >> 4) * 8 + i;
    ws[e] = (f16)W[(co * CIN + ci) * KK + kk];
}

// ---------------- kernel A: global TCN over full srctrg ----------------
template<int CIN, int KK, int DIL, int RES, int RELU>
__device__ __forceinline__ void phaseA(
    const char* __restrict__ inb, char* __restrict__ outb,
    const f16* __restrict__ ws, int eoff, const float* __restrict__ bias, int tid)
{
    constexpr int KB = CIN / 32;
    constexpr int RB = CIN * 2;
    const int lane = tid & 63, wid = tid >> 6;
    const int cg = wid & 3, wg = wid >> 2;
    const int colr = lane & 15, quad = lane >> 4;
    const half8* __restrict__ wp = (const half8*)(ws + eoff);
    half8 wf[2][KK][KB];
#pragma unroll
    for (int ct = 0; ct < 2; ++ct)
#pragma unroll
        for (int kk = 0; kk < KK; ++kk)
#pragma unroll
            for (int kb = 0; kb < KB; ++kb)
                wf[ct][kk][kb] = wp[((((cg * 2 + ct) * KK) + kk) * KB + kb) * 64 + lane];
    const float bv0 = bias[cg * 32 + colr], bv1 = bias[cg * 32 + 16 + colr];
    const int t0 = wg ? 3 : 0, t1 = wg ? 5 : 3;
    for (int t = t0; t < t1; ++t) {
        const int w = t * 16 + colr;
        f32x4 a0 = {0.f, 0.f, 0.f, 0.f}, a1 = {0.f, 0.f, 0.f, 0.f};
#pragma unroll
        for (int kk = 0; kk < KK; ++kk) {
            const int r8 = w + 8 - (KK - 1 - kk) * DIL;   // >= 0 always
            const int rb = r8 * RB, sx = r8 & 7;
#pragma unroll
            for (int kb = 0; kb < KB; ++kb) {
                const half8 a = *(const half8*)(inb + rb + ((((kb * 4 + quad) ^ sx)) << 4));
                a0 = MFMA16(a, wf[0][kk][kb], a0);
                a1 = MFMA16(a, wf[1][kk][kb], a1);
            }
        }
#pragma unroll
        for (int ct = 0; ct < 2; ++ct) {
            const float bv = ct ? bv1 : bv0;
            const int co = cg * 32 + ct * 16 + colr;
#pragma unroll
            for (int j = 0; j < 4; ++j) {
                const int r8o = t * 16 + quad * 4 + j + 8;
                char* p = outb + r8o * 256 + ((((co >> 3) ^ (r8o & 7))) << 4) + ((co & 7) << 1);
                float v = (ct ? a1[j] : a0[j]) + bv;
                if (RELU) v = fmaxf(v, 0.f);
                if (RES)  v = fmaxf(v + (float)*(const f16*)p, 0.f);
                *(f16*)p = (f16)v;
            }
        }
    }
}

extern "C" __global__ void __launch_bounds__(512, 2)
tcn_global(const float* __restrict__ src, const float* __restrict__ trg,
           f16* __restrict__ ws,
           const float* __restrict__ b01, const float* __restrict__ bd0,
           const float* __restrict__ b02, const float* __restrict__ b11,
           const float* __restrict__ b12, const float* __restrict__ b21,
           const float* __restrict__ b22)
{
    __shared__ __align__(16) char sX[88 * 128];
    __shared__ __align__(16) char sH1[88 * 256];
    __shared__ __align__(16) char sH2[88 * 256];
    const int tid = threadIdx.x;
    const int b = blockIdx.x >> 2, chunk = blockIdx.x & 3;
    const int u0 = chunk * 48;
    const float* srcb = src + (size_t)b * LSQ * 64;
    const float* trgb = trg + (size_t)b * TPQ * 64;

    for (int e = tid; e < 80 * 8; e += 512) {
        const int w = e >> 3, gg = e & 7;
        const int p = u0 - 28 + w;
        half8 v = {};
        if (p >= 0 && p < 192) {
            const float* ptr = (p < 168) ? (srcb + p * 64 + gg * 8) : (trgb + (p - 168) * 64 + gg * 8);
            const f4 f0 = *(const f4*)ptr; const f4 f1 = *(const f4*)(ptr + 4);
            v[0] = (f16)f0[0]; v[1] = (f16)f0[1]; v[2] = (f16)f0[2]; v[3] = (f16)f0[3];
            v[4] = (f16)f1[0]; v[5] = (f16)f1[1]; v[6] = (f16)f1[2]; v[7] = (f16)f1[3];
        }
        const int r8 = w + 8;
        *(half8*)(sX + r8 * 128 + ((gg ^ (r8 & 7)) << 4)) = v;
    }
    if (tid < 320) {
        const half8 z = {};
        if (tid < 64)       *(half8*)(sX + tid * 16) = z;
        else if (tid < 192) *(half8*)(sH1 + (tid - 64) * 16) = z;
        else                *(half8*)(sH2 + (tid - 192) * 16) = z;
    }
    __syncthreads();

    phaseA<64, 3, 1, 0, 1>(sX, sH1, ws, E0, b01, tid);
    phaseA<64, 1, 1, 0, 0>(sX, sH2, ws, ED, bd0, tid);
    __syncthreads();
    phaseA<128, 3, 1, 1, 1>(sH1, sH2, ws, E1, b02, tid);   // block0 out -> sH2
    __syncthreads();
    phaseA<128, 3, 2, 0, 1>(sH2, sH1, ws, E2, b11, tid);
    if (chunk == 0) {   // block0 out rows abs [0,40) -> G0
        for (int e = tid; e < 40 * 16; e += 512) {
            const int p = e >> 4, gc = e & 15, r8 = p + 36;
            const half8 v = *(const half8*)(sH2 + r8 * 256 + ((gc ^ (r8 & 7)) << 4));
            *(half8*)(ws + OG0 + (size_t)(b * 40 + p) * 128 + gc * 8) = v;
        }
    }
    __syncthreads();
    phaseA<128, 3, 2, 1, 1>(sH1, sH2, ws, E3, b12, tid);   // block1 out -> sH2
    __syncthreads();
    phaseA<128, 3, 4, 0, 1>(sH2, sH1, ws, E4, b21, tid);
    if (chunk == 0) {   // block1 out rows abs [0,48) -> G1
        for (int e = tid; e < 48 * 16; e += 512) {
            const int p = e >> 4, gc = e & 15, r8 = p + 36;
            const half8 v = *(const half8*)(sH2 + r8 * 256 + ((gc ^ (r8 & 7)) << 4));
            *(half8*)(ws + OG1 + (size_t)(b * 56 + p) * 128 + gc * 8) = v;
        }
    } else if (chunk == 1) {   // block1 out rows abs [48,56) -> G1
        for (int e = tid; e < 8 * 16; e += 512) {
            const int p = 48 + (e >> 4), gc = e & 15, r8 = p - 12;
            const half8 v = *(const half8*)(sH2 + r8 * 256 + ((gc ^ (r8 & 7)) << 4));
            *(half8*)(ws + OG1 + (size_t)(b * 56 + p) * 128 + gc * 8) = v;
        }
    }
    __syncthreads();
    phaseA<128, 3, 4, 1, 1>(sH1, sH2, ws, E5, b22, tid);   // block2 out -> sH2
    __syncthreads();
    for (int e = tid; e < 48 * 16; e += 512) {              // block2 out abs p>=32 -> G2
        const int pl = e >> 4, gc = e & 15, r8 = pl + 36;
        const int p = u0 + pl;
        if (p >= 32) {
            const half8 v = *(const half8*)(sH2 + r8 * 256 + ((gc ^ (r8 & 7)) << 4));
            *(half8*)(ws + OG2 + (size_t)(b * 160 + (p - 32)) * 128 + gc * 8) = v;
        }
    }
}

// ---------------- kernel BC: 4-wave blocks, 2 windows, co-32/wave ct-outer ----------------
template<int CIN, int KK, int DIL, int WPG, int SIN, int SOUT, int RES, int RELU, int NT>
__device__ __forceinline__ void bc_conv(
    const char* __restrict__ inb, char* __restrict__ outb, const char* __restrict__ zrp,
    const f16* __restrict__ ws, int eoff, const float* __restrict__ bias, int tid)
{
    constexpr int KB = CIN / 32;
    constexpr int RB = CIN * 2;
    const int lane = tid & 63, wid = tid >> 6;
    const int colr = lane & 15, quad = lane >> 4;
    const half8* __restrict__ wp = (const half8*)(ws + eoff);
#pragma unroll
    for (int ct = 0; ct < 2; ++ct) {
        half8 wf[KK][KB];
#pragma unroll
        for (int kk = 0; kk < KK; ++kk)
#pragma unroll
            for (int kb = 0; kb < KB; ++kb)
                wf[kk][kb] = wp[((((wid * 2 + ct) * KK) + kk) * KB + kb) * 64 + lane];
        const float bv = bias[wid * 32 + ct * 16 + colr];
#pragma unroll
        for (int t = 0; t < NT; ++t) {
            const int m = t * 16 + colr;
            const int g = m / WPG, w = m - g * WPG;
            f32x4 aA = {0.f, 0.f, 0.f, 0.f}, aB = {0.f, 0.f, 0.f, 0.f};
#pragma unroll
            for (int kk = 0; kk < KK; ++kk) {
                const int wq = w - (KK - 1 - kk) * DIL;
                const int row = g * SIN + wq;
                const char* rb = (wq < 0) ? zrp : (inb + row * RB);
                const int sx = (wq < 0) ? 0 : (row & 7);
#pragma unroll
                for (int kb = 0; kb < KB; ++kb) {
                    const half8 a = *(const half8*)(rb + ((((kb * 4 + quad) ^ sx)) << 4));
                    if (kb & 1) aB = MFMA16(a, wf[kk][kb], aB);
                    else        aA = MFMA16(a, wf[kk][kb], aA);
                }
            }
            const int co = wid * 32 + ct * 16 + colr;
#pragma unroll
            for (int j = 0; j < 4; ++j) {
                const int mo = t * 16 + quad * 4 + j;
                const int go = mo / WPG, wo = mo - go * WPG;
                if (go < 2) {
                    const int row = go * SOUT + wo;
                    char* p = outb + row * 256 + ((((co >> 3) ^ (row & 7))) << 4) + ((co & 7) << 1);
                    float v = aA[j] + aB[j] + bv;
                    if (RELU) v = fmaxf(v, 0.f);
                    if (RES)  v = fmaxf(v + (float)*(const f16*)p, 0.f);
                    *(f16*)p = (f16)v;
                }
            }
        }
    }
}

// P2: block0out = relu( relu(conv2b0(cb1)+b02) + convd(x)+bd0 ) -> BufB rows g*32+w, w<4
__device__ __forceinline__ void bc_p2(
    const char* __restrict__ bx, const char* __restrict__ cb1, char* __restrict__ outB,
    const char* __restrict__ zrp, const f16* __restrict__ ws,
    const float* __restrict__ b02, const float* __restrict__ bd0, int tid)
{
    const int lane = tid & 63, wid = tid >> 6;
    const int colr = lane & 15, quad = lane >> 4;
    const half8* __restrict__ wpA = (const half8*)(ws + E1);
    const half8* __restrict__ wpD = (const half8*)(ws + ED);
#pragma unroll
    for (int ct = 0; ct < 2; ++ct) {
        half8 wfa[3][4], wfd[2];
#pragma unroll
        for (int kk = 0; kk < 3; ++kk)
#pragma unroll
            for (int kb = 0; kb < 4; ++kb)
                wfa[kk][kb] = wpA[((((wid * 2 + ct) * 3) + kk) * 4 + kb) * 64 + lane];
#pragma unroll
        for (int kb = 0; kb < 2; ++kb)
            wfd[kb] = wpD[((wid * 2 + ct) * 2 + kb) * 64 + lane];
        const float ba = b02[wid * 32 + ct * 16 + colr];
        const float bd = bd0[wid * 32 + ct * 16 + colr];
        const int g = colr >> 2, w = colr & 3;
        f32x4 aA = {0.f,0.f,0.f,0.f}, aB = {0.f,0.f,0.f,0.f};
        f32x4 dA = {0.f,0.f,0.f,0.f}, dB = {0.f,0.f,0.f,0.f};
#pragma unroll
        for (int kk = 0; kk < 3; ++kk) {
            const int wq = w - (2 - kk);
            const int row = g * 4 + wq;
            const char* rb = (wq < 0) ? zrp : (cb1 + row * 256);
            const int sx = (wq < 0) ? 0 : (row & 7);
#pragma unroll
            for (int kb = 0; kb < 4; ++kb) {
                const half8 a = *(const half8*)(rb + ((((kb * 4 + quad) ^ sx)) << 4));
                if (kb & 1) aB = MFMA16(a, wfa[kk][kb], aB);
                else        aA = MFMA16(a, wfa[kk][kb], aA);
            }
        }
        {
            const int row = g * 4 + w;
            const char* rb = bx + row * 128;
            const int sx = row & 7;
            const half8 x0 = *(const half8*)(rb + (((0 * 4 + quad) ^ sx) << 4));
            const half8 x1 = *(const half8*)(rb + (((1 * 4 + quad) ^ sx) << 4));
            dA = MFMA16(x0, wfd[0], dA);
            dB = MFMA16(x1, wfd[1], dB);
        }
        const int co = wid * 32 + ct * 16 + colr;
#pragma unroll
        for (int j = 0; j < 4; ++j) {
            const int mo = quad * 4 + j;
            const int go = mo >> 2, wo = mo & 3;
            if (go < 2) {
                const int row = go * 32 + wo;
                char* p = outB + row * 256 + ((((co >> 3) ^ (row & 7))) << 4) + ((co & 7) << 1);
                const float ca = aA[j] + aB[j] + ba;
                const float cd = dA[j] + dB[j] + bd;
                *(f16*)p = (f16)fmaxf(fmaxf(ca, 0.f) + cd, 0.f);
            }
        }
    }
}

// dot of one half8 pair into f32 acc
__device__ __forceinline__ float dot8(half8 kv, half8 vq, float s) {
#if HAS_FDOT2
#pragma unroll
    for (int j2 = 0; j2 < 4; ++j2) {
        half2v a = {kv[2 * j2], kv[2 * j2 + 1]};
        half2v q = {vq[2 * j2], vq[2 * j2 + 1]};
        s = __builtin_amdgcn_fdot2(a, q, s, false);
    }
#else
#pragma unroll
    for (int j = 0; j < 8; ++j) s = fmaf((float)kv[j], (float)vq[j], s);
#endif
    return s;
}

extern "C" __global__ void __launch_bounds__(256, 2)
tcn_bdattn(const float* __restrict__ src, const f16* __restrict__ ws,
           const float* __restrict__ b01, const float* __restrict__ bd0,
           const float* __restrict__ b02, const float* __restrict__ b11,
           const float* __restrict__ b12, const float* __restrict__ b21,
           const float* __restrict__ b22,
           const float* __restrict__ h1w, const float* __restrict__ h1b,
           const float* __restrict__ h2w, const float* __restrict__ h2b,
           float* __restrict__ out)
{
    __shared__ __align__(16) char BufB[64 * 256];   // rows g*32+w
    __shared__ __align__(16) char BufC[64 * 256];   // rows g*32+w; start overlays scb1/sbx
    __shared__ __align__(16) char zr[256];
    __shared__ __align__(16) f16 qh[256];
    __shared__ float qf[256];
    __shared__ float sc[336];
    __shared__ float xs[336];
    __shared__ float cvp[2][2][128];
    char* scb1 = BufC;           // 8 rows x 256B (dead before conv1b1 writes BufC)
    char* sbx  = BufC + 2048;    // 8 rows x 128B

    const int tid = threadIdx.x, lane = tid & 63, wid = tid >> 6;
    const int n0 = blockIdx.x << 1;
    const int tp = n0 >> 7, b0 = n0 & 127;

    if (tid < 16) *(half8*)(zr + tid * 16) = half8{};
    if (tid < 64) {   // stage x rows [0,4) per window (2 win x 4 rows x 8 gran)
        const int g = tid >> 5, w = (tid >> 3) & 3, gg = tid & 7;
        const float* ptr = src + ((size_t)(b0 + g) * LSQ + (tp + w)) * 64 + gg * 8;
        const f4 f0 = *(const f4*)ptr; const f4 f1 = *(const f4*)(ptr + 4);
        half8 v;
        v[0] = (f16)f0[0]; v[1] = (f16)f0[1]; v[2] = (f16)f0[2]; v[3] = (f16)f0[3];
        v[4] = (f16)f1[0]; v[5] = (f16)f1[1]; v[6] = (f16)f1[2]; v[7] = (f16)f1[3];
        const int row = g * 4 + w;
        *(half8*)(sbx + row * 128 + ((gg ^ (row & 7)) << 4)) = v;
    }
    for (int e = tid; e < 384; e += 256) {   // G0 -> BufB rows g*32+[4,16)
        const int gc = e & 15, q = e >> 4;
        const int g = q / 12, pw = 4 + (q - g * 12);
        const half8 v = *(const half8*)(ws + OG0 + (size_t)((b0 + g) * 40 + (tp + pw)) * 128 + gc * 8);
        const int row = g * 32 + pw;
        *(half8*)(BufB + row * 256 + ((gc ^ (row & 7)) << 4)) = v;
    }
    for (int e = tid; e < 512; e += 256) {   // G1 -> BufB rows g*32+[16,32)
        const int gc = e & 15, q = e >> 4;
        const int g = q >> 4, pw = 16 + (q & 15);
        const half8 v = *(const half8*)(ws + OG1 + (size_t)((b0 + g) * 56 + (tp + pw)) * 128 + gc * 8);
        const int row = g * 32 + pw;
        *(half8*)(BufB + row * 256 + ((gc ^ (row & 7)) << 4)) = v;
    }
    if (tid < 32) {    // q (abs tp+168 -> G2 index tp+136) -> qh + qf
        const int g = tid >> 4, gc = tid & 15;
        const half8 v = *(const half8*)(ws + OG2 + ((size_t)(b0 + g) * 160 + tp + 136) * 128 + gc * 8);
        *(half8*)(qh + g * 128 + gc * 8) = v;
#pragma unroll
        for (int j = 0; j < 8; ++j) qf[g * 128 + gc * 8 + j] = (float)v[j];
    }
    __syncthreads();

    bc_conv<64, 3, 1, 4, 4, 4, 0, 1, 1>(sbx, scb1, zr, ws, E0, b01, tid);       // conv1b0 -> scb1
    __syncthreads();
    bc_p2(sbx, scb1, BufB, zr, ws, b02, bd0, tid);                               // block0 -> BufB w<4
    __syncthreads();
    bc_conv<128, 3, 2, 16, 32, 32, 0, 1, 2>(BufB, BufC, zr, ws, E2, b11, tid);  // conv1b1 -> BufC
    __syncthreads();
    bc_conv<128, 3, 2, 16, 32, 32, 1, 1, 2>(BufC, BufB, zr, ws, E3, b12, tid);  // block1 -> BufB w<16
    __syncthreads();
    bc_conv<128, 3, 4, 32, 32, 32, 0, 1, 4>(BufB, BufC, zr, ws, E4, b21, tid);  // conv1b2 -> BufC
    __syncthreads();
    bc_conv<128, 3, 4, 32, 32, 32, 1, 1, 4>(BufC, BufB, zr, ws, E5, b22, tid);  // block2 -> BufB w<32
    __syncthreads();

    // ---- attention: 2 waves per window (g = wid>>1, half h = wid&1) ----
    const int g = wid >> 1, h = wid & 1;
    const int b = b0 + g;
    const f16* __restrict__ g2r = ws + OG2 + ((size_t)b * 160 + tp - 32) * 128;  // +w*128 valid for w>=32
    const int wbase = h * 84;

    // scores for this wave's 84 positions
#pragma unroll
    for (int it = 0; it < 2; ++it) {
        const int w = wbase + it * 64 + lane;
        if (it == 0 || lane < 20) {
            float s = 0.f;
            if (w < 32) {
                const int row = g * 32 + w, sx = row & 7;
                const char* rb = BufB + row * 256;
#pragma unroll
                for (int gc = 0; gc < 16; ++gc) {
                    const half8 kv = *(const half8*)(rb + ((gc ^ sx) << 4));
                    const half8 vq = *(const half8*)(qh + g * 128 + gc * 8);
                    s = dot8(kv, vq, s);
                }
            } else {
                const half8* rb = (const half8*)(g2r + (size_t)w * 128);
#pragma unroll
                for (int gc = 0; gc < 16; ++gc) {
                    const half8 kv = rb[gc];
                    const half8 vq = *(const half8*)(qh + g * 128 + gc * 8);
                    s = dot8(kv, vq, s);
                }
            }
            sc[g * 168 + w] = s;
        }
    }
    __syncthreads();

    // rank-sort (desc, stable) — each wave ranks its 84 elements against all 168
    {
        const int w0i = wbase + lane;
        const int w1i = wbase + 64 + lane;
        const float v0 = sc[g * 168 + w0i];
        const float v1 = (lane < 20) ? sc[g * 168 + w1i] : 0.f;
        int r0 = 0, r1 = 0;
        for (int m2 = 0; m2 < LSQ; ++m2) {
            const float u = sc[g * 168 + m2];
            r0 += (u > v0) || ((u == v0) && (m2 < w0i));
            r1 += (u > v1) || ((u == v1) && (m2 < w1i));
        }
        xs[g * 168 + r0] = v0;
        if (lane < 20) xs[g * 168 + r1] = v1;
    }
    __syncthreads();

    // entmax threshold via shfl scan (computed redundantly in both waves of a window)
    const float mx = xs[g * 168];
    float tau;
    {
        const int i0 = lane * 3;
        const float a0 = (i0     < LSQ) ? (xs[g * 168 + i0]     - mx) * 0.5f : 0.f;
        const float a1 = (i0 + 1 < LSQ) ? (xs[g * 168 + i0 + 1] - mx) * 0.5f : 0.f;
        const float a2 = (i0 + 2 < LSQ) ? (xs[g * 168 + i0 + 2] - mx) * 0.5f : 0.f;
        const float s1 = a0, s2 = a0 + a1, s3 = a0 + a1 + a2;
        const float q1 = a0 * a0, q2 = q1 + a1 * a1, q3 = q2 + a2 * a2;
        float ts = s3, tq = q3;
#pragma unroll
        for (int o = 1; o < 64; o <<= 1) {
            const float us = __shfl_up(ts, o);
            const float uq = __shfl_up(tq, o);
            if (lane >= o) { ts += us; tq += uq; }
        }
        const float eS = ts - s3, eQ = tq - q3;
        float tau0v, tau1v, tau2v; int ind = 0;
#define TAUC(CIDX, CS, CQ, AV, TVAR) { \
        const float rho = (float)(i0 + CIDX + 1); \
        const float mean = (CS) / rho; \
        const float msq = (CQ) / rho; \
        const float ssv = rho * (msq - mean * mean); \
        float delta = (1.f - ssv) / rho; \
        delta = delta > 0.f ? delta : 0.f; \
        TVAR = mean - sqrtf(delta); \
        if (i0 + CIDX < LSQ && TVAR <= (AV)) ++ind; }
        TAUC(0, eS + s1, eQ + q1, a0, tau0v)
        TAUC(1, eS + s2, eQ + q2, a1, tau1v)
        TAUC(2, eS + s3, eQ + q3, a2, tau2v)
#undef TAUC
#pragma unroll
        for (int o = 32; o; o >>= 1) ind += __shfl_xor(ind, o);
        const int sm1 = ind - 1;
        const int srcl = sm1 / 3, c = sm1 - srcl * 3;
        const float tsel = (c == 0) ? tau0v : (c == 1) ? tau1v : tau2v;
        tau = __shfl(tsel, srcl);
    }

    // context partial over this wave's 84 positions (probs recomputed on the fly)
    {
        const int c0 = lane * 2;
        float cv0 = 0.f, cv1 = 0.f;
#pragma unroll 4
        for (int wi = 0; wi < 84; ++wi) {
            const int w = wbase + wi;
            float pz = (sc[g * 168 + w] - mx) * 0.5f - tau;
            pz = fmaxf(pz, 0.f);
            const float pw = pz * pz;
            float k0, k1;
            if (w < 32) {
                const int row = g * 32 + w, sx = row & 7;
                const char* p = BufB + row * 256 + (((c0 >> 3) ^ sx) << 4) + ((c0 & 7) << 1);
                k0 = (float)*(const f16*)p;
                k1 = (float)*(const f16*)(p + 2);
            } else {
                const f16* p = g2r + (size_t)w * 128 + c0;
                k0 = (float)p[0];
                k1 = (float)p[1];
            }
            cv0 = fmaf(pw, k0, cv0);
            cv1 = fmaf(pw, k1, cv1);
        }
        cvp[h][g][c0] = cv0;
        cvp[h][g][c0 + 1] = cv1;
    }
    __syncthreads();

    // heads (wave h==0 of each window)
    if (h == 0) {
        const int c0 = lane * 2;
        const float cva = cvp[0][g][c0]     + cvp[1][g][c0];
        const float cvb = cvp[0][g][c0 + 1] + cvp[1][g][c0 + 1];
        const float q0 = qf[g * 128 + c0], q1 = qf[g * 128 + c0 + 1];
        float s1 = h1w[c0] * cva + h1w[c0 + 1] * cvb + h1w[128 + c0] * q0 + h1w[128 + c0 + 1] * q1;
        float s2 = h2w[c0] * cva + h2w[c0 + 1] * cvb + h2w[128 + c0] * q0 + h2w[128 + c0 + 1] * q1;
#pragma unroll
        for (int o = 32; o; o >>= 1) {
            s1 += __shfl_xor(s1, o);
            s2 += __shfl_xor(s2, o);
        }
        if (lane == 0) {
            const float y1 = s1 + h1b[0];
            const float z = s2 + h2b[0];
            const float sp = (z > 0.f) ? (z + log1pf(expf(-z))) : log1pf(expf(z));
            out[b * TPQ + tp] = y1;
            out[BQ * TPQ + b * TPQ + tp] = sp;
        }
    }
}

extern "C" void kernel_launch(void* const* d_in, const int* in_sizes, int n_in,
                              void* d_out, int out_size, void* d_ws, size_t ws_size,
                              hipStream_t stream) {
    const float* src = (const float*)d_in[0];
    const float* trg = (const float*)d_in[1];
    const float* w01 = (const float*)d_in[2];
    const float* b01 = (const float*)d_in[3];
    const float* w02 = (const float*)d_in[4];
    const float* b02 = (const float*)d_in[5];
    const float* wd0 = (const float*)d_in[6];
    const float* bd0 = (const float*)d_in[7];
    const float* w11 = (const float*)d_in[8];
    const float* b11 = (const float*)d_in[9];
    const float* w12 = (const float*)d_in[10];
    const float* b12 = (const float*)d_in[11];
    const float* w21 = (const float*)d_in[12];
    const float* b21 = (const float*)d_in[13];
    const float* w22 = (const float*)d_in[14];
    const float* b22 = (const float*)d_in[15];
    const float* h1w = (const float*)d_in[16];
    const float* h1b = (const float*)d_in[17];
    const float* h2w = (const float*)d_in[18];
    const float* h2b = (const float*)d_in[19];
    f16* ws = (f16*)d_ws;

    pack_weights<<<dim3((WTOT + 255) / 256), dim3(256), 0, stream>>>(
        w01, wd0, w02, w11, w12, w21, w22, ws);

    tcn_global<<<dim3(BQ * 4), dim3(512), 0, stream>>>(
        src, trg, ws, b01, bd0, b02, b11, b12, b21, b22);

    tcn_bdattn<<<dim3(TPQ * BQ / 2), dim3(256), 0, stream>>>(
        src, ws, b01, bd0, b02, b11, b12, b21, b22,
        h1w, h1b, h2w, h2b, (float*)d_out);
}